// Round 5
// baseline (1560.258 us; speedup 1.0000x reference)
//
#include <hip/hip_runtime.h>
#include <cstdint>
#include <cstddef>

// ---------- types ----------
typedef __attribute__((ext_vector_type(8))) __bf16 bf16x8;   // MFMA A/B frag (4 VGPRs)
typedef __attribute__((ext_vector_type(4))) float f32x4;     // MFMA C/D frag

__device__ __forceinline__ unsigned short f2bf(float f) {    // RNE float->bf16
  unsigned int u = __float_as_uint(f);
  u += 0x7FFFu + ((u >> 16) & 1u);
  return (unsigned short)(u >> 16);
}
__device__ __forceinline__ float bf2f(unsigned short h) {
  return __uint_as_float(((unsigned int)h) << 16);
}

// ---------- runtime dtype detection ----------
// If the float tensors are fp32, the even-index 16-bit words are low mantissa
// halves (uniform bits): exponent-looking field plausible only ~8% of the time.
// If bf16, every word of N(0,1) data has exponent in [115,135].
__device__ __forceinline__ int detect_f32(const unsigned short* det) {
  int cnt = 0;
#pragma unroll
  for (int i = 0; i < 32; ++i) {
    const unsigned int e = (det[2 * i] >> 7) & 0xFF;
    cnt += (e >= 115 && e <= 135) ? 1 : 0;
  }
  return cnt < 16;   // 1 => buffers are fp32, 0 => bf16
}

// dual-dtype scalar load/store (offsets in ELEMENTS)
__device__ __forceinline__ float loadf(const void* b, size_t i, int f32) {
  return f32 ? ((const float*)b)[i] : bf2f(((const unsigned short*)b)[i]);
}
__device__ __forceinline__ void storef(void* b, size_t i, float v, int f32) {
  if (f32) ((float*)b)[i] = v;
  else     ((unsigned short*)b)[i] = f2bf(v);
}
// dual-dtype 8-element fragment load -> bf16x8 (offset in ELEMENTS, 8-aligned)
__device__ __forceinline__ bf16x8 load8(const void* base, size_t elem, int f32) {
  if (f32) {
    const float* p = (const float*)base + elem;
    bf16x8 r;
#pragma unroll
    for (int i = 0; i < 8; ++i) ((unsigned short*)&r)[i] = f2bf(p[i]);
    return r;
  }
  return *(const bf16x8*)((const unsigned short*)base + elem);
}

// ---------------------------------------------------------------------------
// GEMM: C[m,n] = sum_k A[m,k] * W[n,k]  (both K-contiguous, fp32 acc, MFMA bf16)
// 128x128 tile, BK=32, 256 thr = 4 waves, each wave 64x64 via 4x4 of 16x16x32.
// amode/wmode/cmode: 0 = operand is always bf16 (workspace), 1 = follows the
// detected input/output dtype. coff: element offset added to C index.
// mode 0: C idx = m*N+n.  mode 1: scatter ((b*32+h)*S + t0 + t)*64 + d.
// ---------------------------------------------------------------------------
__global__ __launch_bounds__(256) void gemm_bt_kernel(
    const void* __restrict__ A, const void* __restrict__ W, void* __restrict__ C,
    const unsigned short* __restrict__ det,
    int amode, int wmode, int cmode, size_t coff,
    int N, int K, int mode, int S, int t0)
{
  __shared__ __align__(16) unsigned short As[128 * 32];
  __shared__ __align__(16) unsigned short Bs[128 * 32];
  const int f32  = detect_f32(det);
  const int af32 = amode & f32, wf32 = wmode & f32, cf32 = cmode & f32;

  const int tid  = threadIdx.x;
  const int lane = tid & 63;
  const int wave = tid >> 6;
  const int quad = lane >> 4;
  const int l16  = lane & 15;
  const int mBase = blockIdx.x * 128;
  const int nBase = blockIdx.y * 128;
  const int wm = (wave >> 1) * 64;
  const int wn = (wave & 1) * 64;

  const int row0 = tid >> 2,          kc0 = (tid & 3) << 3;
  const int row1 = (256 + tid) >> 2,  kc1 = ((256 + tid) & 3) << 3;

  f32x4 acc[4][4];
#pragma unroll
  for (int i = 0; i < 4; ++i)
#pragma unroll
    for (int j = 0; j < 4; ++j) acc[i][j] = f32x4{0.f, 0.f, 0.f, 0.f};

  for (int kb = 0; kb < K; kb += 32) {
    const bf16x8 a0 = load8(A, (size_t)(mBase + row0) * K + kb + kc0, af32);
    const bf16x8 a1 = load8(A, (size_t)(mBase + row1) * K + kb + kc1, af32);
    const bf16x8 b0 = load8(W, (size_t)(nBase + row0) * K + kb + kc0, wf32);
    const bf16x8 b1 = load8(W, (size_t)(nBase + row1) * K + kb + kc1, wf32);
    __syncthreads();  // previous iteration's readers done
    *(bf16x8*)&As[(size_t)tid * 8]         = a0;
    *(bf16x8*)&As[(size_t)(256 + tid) * 8] = a1;
    *(bf16x8*)&Bs[(size_t)tid * 8]         = b0;
    *(bf16x8*)&Bs[(size_t)(256 + tid) * 8] = b1;
    __syncthreads();  // staging visible

    bf16x8 af[4], bfr[4];
#pragma unroll
    for (int i = 0; i < 4; ++i)
      af[i]  = *(const bf16x8*)&As[(wm + i * 16 + l16) * 32 + quad * 8];
#pragma unroll
    for (int j = 0; j < 4; ++j)
      bfr[j] = *(const bf16x8*)&Bs[(wn + j * 16 + l16) * 32 + quad * 8];
#pragma unroll
    for (int i = 0; i < 4; ++i)
#pragma unroll
      for (int j = 0; j < 4; ++j)
        acc[i][j] = __builtin_amdgcn_mfma_f32_16x16x32_bf16(af[i], bfr[j], acc[i][j], 0, 0, 0);
  }

  // epilogue: C/D layout col=lane&15, row=quad*4+reg
#pragma unroll
  for (int i = 0; i < 4; ++i) {
#pragma unroll
    for (int j = 0; j < 4; ++j) {
#pragma unroll
      for (int r = 0; r < 4; ++r) {
        const int m = mBase + wm + i * 16 + quad * 4 + r;
        const int n = nBase + wn + j * 16 + l16;
        size_t idx;
        if (mode == 0) {
          idx = (size_t)m * N + n;
        } else {
          const int b = m >> 8, t = m & 255;
          const int hh = n >> 6, d = n & 63;
          idx = (((size_t)(b * 32 + hh)) * S + (t0 + t)) * 64 + d;
        }
        storef(C, coff + idx, acc[i][j][r], cf32);
      }
    }
  }
}

// ---------------------------------------------------------------------------
// copy past slabs into outputs: new_{k,v}[0:256] = past_{k,v}[256:512].
// One block per (b,h). Byte-level uint4 copies sized by detected dtype.
// ---------------------------------------------------------------------------
__global__ __launch_bounds__(256) void copy_kernel(
    const void* __restrict__ past_k, const void* __restrict__ past_v,
    void* __restrict__ dout, const unsigned short* __restrict__ det)
{
  const int f32 = detect_f32(det);
  const int es  = f32 ? 4 : 2;
  const int bh  = blockIdx.x;
  const int tid = threadIdx.x;
  const size_t srcOff  = ((size_t)bh * 512 + 256) * 64 * es;
  const size_t dstKOff = ((size_t)8388608  + (size_t)bh * 512 * 64) * es;
  const size_t dstVOff = ((size_t)25165824 + (size_t)bh * 512 * 64) * es;
  const uint4* sK = (const uint4*)((const char*)past_k + srcOff);
  const uint4* sV = (const uint4*)((const char*)past_v + srcOff);
  uint4* dK = (uint4*)((char*)dout + dstKOff);
  uint4* dV = (uint4*)((char*)dout + dstVOff);
  const int n4 = 16384 * es / 16;  // slab = 256 rows * 64 elems
  for (int c = tid; c < n4; c += 256) { dK[c] = sK[c]; dV[c] = sV[c]; }
}

// ---------------------------------------------------------------------------
// RoPE: which=0 -> q_ws in-place (bf16 ws); which=1 -> new_k[256:] (in d_out,
// detected dtype) -> krot_ws (bf16).
// ---------------------------------------------------------------------------
__global__ __launch_bounds__(256) void rope_kernel(
    const int* __restrict__ pos_p,
    unsigned short* __restrict__ qbuf,
    const void* __restrict__ dout,
    unsigned short* __restrict__ krot,
    const unsigned short* __restrict__ det)
{
  const int f32 = detect_f32(det);
  const int gid = blockIdx.x * 256 + threadIdx.x;
  const int which = gid >> 22;               // 2^22 pairs per tensor
  const int pi = gid & ((1 << 22) - 1);
  const int i  = pi & 31;
  const int t  = (pi >> 5) & 255;
  const int bh = pi >> 13;
  const float pos  = (float)(*pos_p + t);
  const float freq = expf(-(float)i * 0.2878231366242557f);  // 10000^(-i/32)
  float sn, cs;
  sincosf(pos * freq, &sn, &cs);
  if (which == 0) {
    unsigned short* p = qbuf + (((size_t)bh * 256 + t) * 64 + 2 * i);
    const float a = bf2f(p[0]), b2 = bf2f(p[1]);
    p[0] = f2bf(a * cs - b2 * sn);
    p[1] = f2bf(a * sn + b2 * cs);
  } else {
    const size_t src = 8388608 + (((size_t)bh * 512 + 256 + t) * 64 + 2 * i);
    unsigned short* dp = krot + (((size_t)bh * 256 + t) * 64 + 2 * i);
    const float a = loadf(dout, src, f32), b2 = loadf(dout, src + 1, f32);
    dp[0] = f2bf(a * cs - b2 * sn);
    dp[1] = f2bf(a * sn + b2 * cs);
  }
}

// ---------------------------------------------------------------------------
// Flash-style attention. One block per (b,h). Strip-groups processed in
// lockstep across all 4 waves so the P LDS round-trip is barrier-protected.
// Mask: key j visible iff j <= t + 256.
// ---------------------------------------------------------------------------
__global__ __launch_bounds__(256) void attn_kernel(
    const unsigned short* __restrict__ q,      // (BH,256,64) roped, bf16 ws
    const void* __restrict__ past_k,           // (BH,512,64) input dtype
    const unsigned short* __restrict__ k_rot,  // (BH,256,64) roped, bf16 ws
    const void* __restrict__ past_v,           // (BH,512,64) input dtype
    const void* __restrict__ dout,             // new_v at elem offset 25165824
    unsigned short* __restrict__ attn_out,     // (B,256,2048) bf16 ws
    const unsigned short* __restrict__ det)
{
  const int f32 = detect_f32(det);
  const int bh = blockIdx.x;
  const int b  = bh >> 5;
  const int h  = bh & 31;
  const int tid  = threadIdx.x;
  const int wave = tid >> 6;
  const int lane = tid & 63;
  const int quad = lane >> 4;
  const int l16  = lane & 15;
  const float NEG = -1e30f;

  __shared__ __align__(16) unsigned short p_lds[4][16 * 32];  // wave-private P
  unsigned short* pw = p_lds[wave];
  volatile unsigned short* pwv = pw;

  const unsigned short* qb_ptr = q + (size_t)bh * 256 * 64;
  const unsigned short* krot   = k_rot + (size_t)bh * 256 * 64;
  const size_t kpastBase = ((size_t)bh * 512 + 256) * 64;  // elems into past_k
  const size_t vpastBase = ((size_t)bh * 512 + 256) * 64;  // elems into past_v
  const size_t vcurBase  = 25165824 + (size_t)bh * 512 * 64;  // elems into dout

  for (int g = 0; g < 4; ++g) {
    const int s = g * 4 + wave;
    const int qbase = s * 16;
    const bf16x8 aq0 = *(const bf16x8*)&qb_ptr[(qbase + l16) * 64 + quad * 8];
    const bf16x8 aq1 = *(const bf16x8*)&qb_ptr[(qbase + l16) * 64 + 32 + quad * 8];
    f32x4 o[4];
#pragma unroll
    for (int nt = 0; nt < 4; ++nt) o[nt] = f32x4{0.f, 0.f, 0.f, 0.f};
    float m_i[4], l_i[4];
#pragma unroll
    for (int r = 0; r < 4; ++r) { m_i[r] = NEG; l_i[r] = 0.f; }

    const int np_me  = ((qbase + 271) >> 5) + 1;        // this wave's pairs
    const int np_max = ((g * 64 + 319) >> 5) + 1;       // group max (wave 3)

    for (int p = 0; p < np_max; ++p) {
      const int active = (p < np_me);
      const int j0 = p * 32;
      if (active) {
        f32x4 s0 = f32x4{0.f, 0.f, 0.f, 0.f};
        f32x4 s1 = f32x4{0.f, 0.f, 0.f, 0.f};
#pragma unroll
        for (int half = 0; half < 2; ++half) {
          const int j = j0 + half * 16 + l16;
          bf16x8 kb0, kb1;
          if (j < 256) {
            kb0 = load8(past_k, kpastBase + (size_t)j * 64 + quad * 8, f32);
            kb1 = load8(past_k, kpastBase + (size_t)j * 64 + 32 + quad * 8, f32);
          } else {
            const unsigned short* kr = krot + (size_t)(j - 256) * 64;
            kb0 = *(const bf16x8*)&kr[quad * 8];
            kb1 = *(const bf16x8*)&kr[32 + quad * 8];
          }
          f32x4& sx = half ? s1 : s0;
          sx = __builtin_amdgcn_mfma_f32_16x16x32_bf16(aq0, kb0, sx, 0, 0, 0);
          sx = __builtin_amdgcn_mfma_f32_16x16x32_bf16(aq1, kb1, sx, 0, 0, 0);
        }
        // online softmax (row = qbase + quad*4 + r; cols j0+{0,16}+l16)
#pragma unroll
        for (int r = 0; r < 4; ++r) {
          const int qrow = qbase + quad * 4 + r;
          float v0 = s0[r] * 0.125f;
          float v1 = s1[r] * 0.125f;
          if (j0 + l16 > qrow + 256)      v0 = NEG;
          if (j0 + 16 + l16 > qrow + 256) v1 = NEG;
          float t = fmaxf(v0, v1);
          t = fmaxf(t, __shfl_xor(t, 1));
          t = fmaxf(t, __shfl_xor(t, 2));
          t = fmaxf(t, __shfl_xor(t, 4));
          t = fmaxf(t, __shfl_xor(t, 8));
          const float mnew = fmaxf(m_i[r], t);
          const float alpha = __expf(m_i[r] - mnew);
          m_i[r] = mnew;
          const float p0 = __expf(v0 - mnew);
          const float p1 = __expf(v1 - mnew);
          float rs = p0 + p1;
          rs += __shfl_xor(rs, 1);
          rs += __shfl_xor(rs, 2);
          rs += __shfl_xor(rs, 4);
          rs += __shfl_xor(rs, 8);
          l_i[r] = l_i[r] * alpha + rs;
          pwv[(quad * 4 + r) * 32 + l16]      = f2bf(p0);
          pwv[(quad * 4 + r) * 32 + 16 + l16] = f2bf(p1);
#pragma unroll
          for (int nt = 0; nt < 4; ++nt) o[nt][r] *= alpha;
        }
      }
      __syncthreads();  // P writes complete (drains each wave's DS queue)
      if (active) {
        const bf16x8 ap = *(const bf16x8*)&pw[l16 * 32 + quad * 8];
#pragma unroll
        for (int nt = 0; nt < 4; ++nt) {
          const int d = nt * 16 + l16;
          alignas(16) unsigned short bvv[8];
#pragma unroll
          for (int jj = 0; jj < 8; ++jj) {
            const int j = j0 + quad * 8 + jj;
            const float v = (j < 256)
                ? loadf(past_v, vpastBase + (size_t)j * 64 + d, f32)
                : loadf(dout,   vcurBase  + (size_t)j * 64 + d, f32);
            bvv[jj] = f2bf(v);
          }
          o[nt] = __builtin_amdgcn_mfma_f32_16x16x32_bf16(ap, *(const bf16x8*)bvv, o[nt], 0, 0, 0);
        }
      }
      __syncthreads();  // reads complete before next iteration's writes
    }
    // epilogue: normalize, write (b, t, h*64 + nt*16 + l16) as bf16 ws
#pragma unroll
    for (int r = 0; r < 4; ++r) {
      const float inv = 1.0f / l_i[r];
      const int t = qbase + quad * 4 + r;
#pragma unroll
      for (int nt = 0; nt < 4; ++nt) {
        attn_out[((size_t)(b * 256 + t)) * 2048 + h * 64 + nt * 16 + l16] =
            f2bf(o[nt][r] * inv);
      }
    }
  }
}

// ---------------------------------------------------------------------------
extern "C" void kernel_launch(void* const* d_in, const int* in_sizes, int n_in,
                              void* d_out, int out_size, void* d_ws, size_t ws_size,
                              hipStream_t stream)
{
  const void* x      = d_in[0];
  const void* past_k = d_in[1];
  const void* past_v = d_in[2];
  const void* Wq     = d_in[3];
  const void* Wk     = d_in[4];
  const void* Wv     = d_in[5];
  const void* Wo     = d_in[6];
  const int* pos_p   = (const int*)d_in[7];
  const unsigned short* det = (const unsigned short*)x;  // dtype probe

  // workspace (always bf16 internally): 48 MiB
  unsigned short* ws      = (unsigned short*)d_ws;
  unsigned short* q_ws    = ws;                          // (BH,256,64)  16 MiB
  unsigned short* krot_ws = ws + 8388608;                // (BH,256,64)  16 MiB
  unsigned short* ao_ws   = ws + 16777216;               // (B,256,2048) 16 MiB

  const dim3 gg(32, 16), gb(256);
  // projections: Q -> bf16 ws scatter; K/V -> d_out (detected dtype) scatter
  hipLaunchKernelGGL(gemm_bt_kernel, gg, gb, 0, stream, x, Wq, (void*)q_ws, det,
                     1, 1, 0, (size_t)0,        2048, 2048, 1, 256, 0);
  hipLaunchKernelGGL(gemm_bt_kernel, gg, gb, 0, stream, x, Wk, d_out, det,
                     1, 1, 1, (size_t)8388608,  2048, 2048, 1, 512, 256);
  hipLaunchKernelGGL(gemm_bt_kernel, gg, gb, 0, stream, x, Wv, d_out, det,
                     1, 1, 1, (size_t)25165824, 2048, 2048, 1, 512, 256);
  // past slabs -> outputs
  hipLaunchKernelGGL(copy_kernel, dim3(512), gb, 0, stream, past_k, past_v, d_out, det);
  // RoPE: q in-place (bf16 ws); new_k[256:] (d_out) -> krot_ws (bf16)
  hipLaunchKernelGGL(rope_kernel, dim3(32768), gb, 0, stream, pos_p, q_ws, d_out, krot_ws, det);
  // attention -> ao_ws (bf16)
  hipLaunchKernelGGL(attn_kernel, dim3(512), gb, 0, stream,
                     q_ws, past_k, krot_ws, past_v, d_out, ao_ws, det);
  // output projection -> d_out (detected dtype)
  hipLaunchKernelGGL(gemm_bt_kernel, gg, gb, 0, stream, (const void*)ao_ws, Wo, d_out, det,
                     0, 1, 1, (size_t)0,        2048, 2048, 0, 0, 0);
}